// Round 3
// baseline (228.276 us; speedup 1.0000x reference)
//
#include <hip/hip_runtime.h>

#define N_NODES 4096
#define FIN     512
#define FOUT    256
#define NSPLIT  4
#define NTILES  ((N_NODES / NSPLIT) / 64)   // 16

typedef __attribute__((ext_vector_type(8))) short bf16x8s;
typedef __attribute__((ext_vector_type(4))) float f32x4;
typedef __attribute__((ext_vector_type(8))) unsigned short u16x8;
typedef unsigned short u16;
typedef unsigned int   u32;
typedef unsigned long long u64;

__device__ inline u16 f2b(float f) {
    union { float f; unsigned int u; } v; v.f = f;
    unsigned int r = v.u + 0x7fffu + ((v.u >> 16) & 1u);   // RTNE
    return (u16)(r >> 16);
}

// ---------------------------------------------------------------------------
// prep: [0,1024)    h fp32 -> hb bf16
//       [1024,2048) adj_n|adj_d -> bitmask (ballot, fully coalesced stream)
//       [2048,2112) W_b -> WTb bf16 transposed [n][k]
//       [2112]      zero s1/s2
// ---------------------------------------------------------------------------
__global__ __launch_bounds__(256) void prep_kernel(
    const float* __restrict__ h, const float* __restrict__ Wn,
    const float* __restrict__ Wd,
    const int* __restrict__ adjn, const int* __restrict__ adjd,
    u16* __restrict__ hb, u16* __restrict__ WTb, u64* __restrict__ bits64,
    float* __restrict__ s12)
{
    __shared__ u16 tl[64 * 72];
    const int t = threadIdx.x;
    const int bid = blockIdx.x;

    if (bid < 1024) {                       // h convert
        int idx = (bid * 256 + t) * 8;
        float4 f0 = *(const float4*)&h[idx];
        float4 f1 = *(const float4*)&h[idx + 4];
        u16x8 o;
        o[0]=f2b(f0.x); o[1]=f2b(f0.y); o[2]=f2b(f0.z); o[3]=f2b(f0.w);
        o[4]=f2b(f1.x); o[5]=f2b(f1.y); o[6]=f2b(f1.z); o[7]=f2b(f1.w);
        *(u16x8*)&hb[idx] = o;
    } else if (bid < 2048) {                // adj -> bits
        const int lane = t & 63;
        const long base0 = ((long)(bid - 1024) * 4 + (t >> 6)) * 8192;
        #pragma unroll 2
        for (int it = 0; it < 32; ++it) {
            long base = base0 + (long)it * 256;
            const int* p = (base < (1L << 24)) ? (adjn + base)
                                               : (adjd + (base - (1L << 24)));
            int v0 = p[lane], v1 = p[lane + 64], v2 = p[lane + 128], v3 = p[lane + 192];
            u64 b0 = __ballot(v0 > 0);
            u64 b1 = __ballot(v1 > 0);
            u64 b2 = __ballot(v2 > 0);
            u64 b3 = __ballot(v3 > 0);
            if (lane == 0) {
                u64* d = bits64 + (base >> 6);
                d[0] = b0; d[1] = b1; d[2] = b2; d[3] = b3;
            }
        }
    } else if (bid < 2112) {                // W transpose+convert, 64x64 tiles
        int id = bid - 2048;
        int kx = id & 7, ny = (id >> 3) & 3, b = id >> 5;
        const float* W = b ? Wd : Wn;
        int k0 = kx * 64, n0 = ny * 64;
        int kr = t >> 2, nc0 = (t & 3) * 16;
        const float* src = W + (size_t)(k0 + kr) * FOUT + n0 + nc0;
        #pragma unroll
        for (int jv = 0; jv < 4; ++jv) {
            float4 f = *(const float4*)(src + jv * 4);
            tl[(nc0 + jv * 4 + 0) * 72 + kr] = f2b(f.x);
            tl[(nc0 + jv * 4 + 1) * 72 + kr] = f2b(f.y);
            tl[(nc0 + jv * 4 + 2) * 72 + kr] = f2b(f.z);
            tl[(nc0 + jv * 4 + 3) * 72 + kr] = f2b(f.w);
        }
        __syncthreads();
        int n = t >> 2, kc0 = (t & 3) * 16;
        u16* dst = WTb + ((size_t)b << 17) + (size_t)(n0 + n) * FIN + k0 + kc0;
        *(uint4*)dst       = *(uint4*)&tl[n * 72 + kc0];
        *(uint4*)(dst + 8) = *(uint4*)&tl[n * 72 + kc0 + 8];
    } else {                                // zero s1,s2 (16384 floats)
        float4 z = {0.f, 0.f, 0.f, 0.f};
        float4* p4 = (float4*)s12;
        #pragma unroll
        for (int k = 0; k < 16; ++k) p4[k * 256 + t] = z;
    }
}

// ---------------------------------------------------------------------------
// wh_gemm: WhT[b][n][i] = (hb @ W_b)[i][n]; epilogue also accumulates
// s1[b][i] += sum_n C[i][n]*a1[n], s2 likewise (atomics across n0-blocks).
// grid (64, 4, 2).
// ---------------------------------------------------------------------------
__global__ __launch_bounds__(256) void wh_gemm_kernel(
    const u16* __restrict__ hb, const u16* __restrict__ WTb,
    const float* __restrict__ a1n, const float* __restrict__ a2n,
    const float* __restrict__ a1d, const float* __restrict__ a2d,
    u16* __restrict__ WhT, float* __restrict__ s1, float* __restrict__ s2)
{
    __shared__ u16 smem[8192];
    u16* a_lds = smem;
    u16* b_lds = smem + 4096;

    const int t = threadIdx.x, lane = t & 63, w = t >> 6;
    const int q = lane >> 4, ln = lane & 15;
    const int i0 = blockIdx.x * 64, n0 = blockIdx.y * 64, b = blockIdx.z;
    const u16* wt = WTb + ((size_t)b << 17);

    f32x4 acc[4];
    #pragma unroll
    for (int i = 0; i < 4; ++i) acc[i] = (f32x4){0.f, 0.f, 0.f, 0.f};

    for (int kt = 0; kt < 8; ++kt) {
        const int k0 = kt * 64;
        __syncthreads();
        #pragma unroll
        for (int it = 0; it < 2; ++it) {
            int chunk = it * 256 + t;
            int r = chunk >> 3, kc = chunk & 7;
            const u16* g = hb + (size_t)(i0 + r) * FIN + k0 + ((kc ^ (r & 7)) * 8);
            u16* l = a_lds + (it * 256 + w * 64) * 8;
            __builtin_amdgcn_global_load_lds(
                (const __attribute__((address_space(1))) void*)g,
                (__attribute__((address_space(3))) void*)l, 16, 0, 0);
        }
        #pragma unroll
        for (int it = 0; it < 2; ++it) {
            int chunk = it * 256 + t;
            int n = chunk >> 3, kc = chunk & 7;
            const u16* g = wt + (size_t)(n0 + n) * FIN + k0 + ((kc ^ (n & 7)) * 8);
            u16* l = b_lds + (it * 256 + w * 64) * 8;
            __builtin_amdgcn_global_load_lds(
                (const __attribute__((address_space(1))) void*)g,
                (__attribute__((address_space(3))) void*)l, 16, 0, 0);
        }
        __syncthreads();
        #pragma unroll
        for (int ks = 0; ks < 2; ++ks) {
            int sw = ((ks * 4 + q) ^ (ln & 7)) * 8;
            bf16x8s af = *(const bf16x8s*)&a_lds[(w * 16 + ln) * 64 + sw];
            #pragma unroll
            for (int nt = 0; nt < 4; ++nt) {
                bf16x8s bfv = *(const bf16x8s*)&b_lds[(nt * 16 + ln) * 64 + sw];
                acc[nt] = __builtin_amdgcn_mfma_f32_16x16x32_bf16(af, bfv, acc[nt], 0, 0, 0);
            }
        }
    }

    // s1/s2 partials from fp32 accumulators
    {
        const float* a1 = b ? a1d : a1n;
        const float* a2 = b ? a2d : a2n;
        float s1p[4] = {0.f, 0.f, 0.f, 0.f};
        float s2p[4] = {0.f, 0.f, 0.f, 0.f};
        #pragma unroll
        for (int nt = 0; nt < 4; ++nt) {
            float va1 = a1[n0 + nt * 16 + ln];
            float va2 = a2[n0 + nt * 16 + ln];
            #pragma unroll
            for (int r = 0; r < 4; ++r) {
                s1p[r] += acc[nt][r] * va1;
                s2p[r] += acc[nt][r] * va2;
            }
        }
        #pragma unroll
        for (int r = 0; r < 4; ++r) {
            #pragma unroll
            for (int off = 8; off >= 1; off >>= 1) {
                s1p[r] += __shfl_xor(s1p[r], off);
                s2p[r] += __shfl_xor(s2p[r], off);
            }
            if (ln == 0) {
                int row = i0 + w * 16 + q * 4 + r;
                atomicAdd(&s1[b * N_NODES + row], s1p[r]);
                atomicAdd(&s2[b * N_NODES + row], s2p[r]);
            }
        }
    }

    __syncthreads();
    #pragma unroll
    for (int nt = 0; nt < 4; ++nt)
        #pragma unroll
        for (int r = 0; r < 4; ++r)
            smem[(nt * 16 + ln) * 72 + (w * 16 + q * 4 + r)] = f2b(acc[nt][r]);
    __syncthreads();
    {
        const int nl = t >> 2, is = (t & 3) * 16;
        u16* dst = WhT + ((size_t)b << 20) + (size_t)(n0 + nl) * N_NODES + i0 + is;
        *(uint4*)dst       = *(uint4*)&smem[nl * 72 + is];
        *(uint4*)(dst + 8) = *(uint4*)&smem[nl * 72 + is + 8];
    }
}

// ---------------------------------------------------------------------------
// attn: 32 rows x 1024-j per block; adj from bitmask; bits+s2 prefetched a
// tile ahead so P-gen never waits on a load. grid (128, NSPLIT, 2).
// ---------------------------------------------------------------------------
__global__ __launch_bounds__(256, 4) void attn_kernel(
    const u32* __restrict__ bits,
    const u16* __restrict__ WhT,
    const float* __restrict__ s1, const float* __restrict__ s2,
    float* __restrict__ num_ws, float* __restrict__ den_ws)
{
    __shared__ u16 wht_lds[256 * 64];   // swizzled [n][kchunk^(n&7)], 32 KB
    __shared__ u16 p_lds[32 * 64];      // swizzled, 4 KB
    __shared__ float den_lds[32];

    const int t = threadIdx.x, lane = t & 63, w = t >> 6;
    const int q = lane >> 4, ln = lane & 15;
    const int b = blockIdx.z, split = blockIdx.y;
    const int i0 = blockIdx.x * 32;

    const u16* whtB = WhT + ((size_t)b << 20);
    const float* s1b = s1 + b * N_NODES;
    const float* s2b = s2 + b * N_NODES;

    const int pr = t >> 3;              // P row 0..31
    const int cw = t & 7;               // P k-chunk 0..7
    const int pc = cw * 8;
    const int bsh = (cw & 3) * 8;
    const float s1v = s1b[i0 + pr];
    const u32* bitrow = bits + (size_t)b * (N_NODES * N_NODES / 32)
                             + (size_t)(i0 + pr) * (N_NODES / 32) + (cw >> 2);

    if (t < 32) den_lds[t] = 0.f;

    f32x4 acc[2][4];
    #pragma unroll
    for (int mt = 0; mt < 2; ++mt)
        #pragma unroll
        for (int nt = 0; nt < 4; ++nt) acc[mt][nt] = (f32x4){0.f, 0.f, 0.f, 0.f};

    const int jbase = split * (N_NODES / NSPLIT);
    u32 bw_pf = bitrow[jbase >> 5];
    float4 sv0_pf = *(const float4*)&s2b[jbase + pc];
    float4 sv1_pf = *(const float4*)&s2b[jbase + pc + 4];

    for (int jt = 0; jt < NTILES; ++jt) {
        const int j0 = jbase + jt * 64;
        __syncthreads();
        #pragma unroll
        for (int it = 0; it < 8; ++it) {   // stage 256n x 64j WhT tile
            int chunk = it * 256 + t;
            int n = chunk >> 3, kc = chunk & 7;
            const u16* g = whtB + (size_t)n * N_NODES + j0 + ((kc ^ (n & 7)) * 8);
            u16* l = wht_lds + (it * 256 + w * 64) * 8;
            __builtin_amdgcn_global_load_lds(
                (const __attribute__((address_space(1))) void*)g,
                (__attribute__((address_space(3))) void*)l, 16, 0, 0);
        }
        u32 bw = bw_pf;
        float4 sv0 = sv0_pf, sv1 = sv1_pf;
        if (jt < NTILES - 1) {             // prefetch next tile
            bw_pf = bitrow[(j0 + 64) >> 5];
            sv0_pf = *(const float4*)&s2b[j0 + 64 + pc];
            sv1_pf = *(const float4*)&s2b[j0 + 64 + pc + 4];
        }
        u32 mask8 = (bw >> bsh) & 0xffu;
        float svf[8] = {sv0.x, sv0.y, sv0.z, sv0.w, sv1.x, sv1.y, sv1.z, sv1.w};
        float den_part = 0.f;
        u16x8 pk;
        #pragma unroll
        for (int jj = 0; jj < 8; ++jj) {
            float x = s1v + svf[jj];
            float lr = fmaxf(x, 0.2f * x);
            float p = ((mask8 >> jj) & 1u) ? __expf(lr) : 0.f;
            den_part += p;
            pk[jj] = f2b(p);
        }
        den_part += __shfl_down(den_part, 4, 8);
        den_part += __shfl_down(den_part, 2, 8);
        den_part += __shfl_down(den_part, 1, 8);
        if ((t & 7) == 0) den_lds[pr] += den_part;
        *(u16x8*)&p_lds[pr * 64 + ((cw ^ (pr & 7)) * 8)] = pk;
        __syncthreads();
        #pragma unroll
        for (int ks = 0; ks < 2; ++ks) {
            int sw = ((ks * 4 + q) ^ (ln & 7)) * 8;
            bf16x8s a0  = *(const bf16x8s*)&p_lds[ln * 64 + sw];
            bf16x8s a1f = *(const bf16x8s*)&p_lds[(16 + ln) * 64 + sw];
            #pragma unroll
            for (int nt = 0; nt < 4; ++nt) {
                bf16x8s bfv = *(const bf16x8s*)&wht_lds[(w * 64 + nt * 16 + ln) * 64 + sw];
                acc[0][nt] = __builtin_amdgcn_mfma_f32_16x16x32_bf16(a0,  bfv, acc[0][nt], 0, 0, 0);
                acc[1][nt] = __builtin_amdgcn_mfma_f32_16x16x32_bf16(a1f, bfv, acc[1][nt], 0, 0, 0);
            }
        }
    }
    const size_t pbase = (size_t)(b * NSPLIT + split) * N_NODES;
    #pragma unroll
    for (int mt = 0; mt < 2; ++mt)
        #pragma unroll
        for (int r = 0; r < 4; ++r) {
            int row = mt * 16 + q * 4 + r;
            #pragma unroll
            for (int nt = 0; nt < 4; ++nt)
                num_ws[(pbase + i0 + row) * FOUT + w * 64 + nt * 16 + ln] = acc[mt][nt][r];
        }
    if (t < 32) den_ws[pbase + i0 + t] = den_lds[t];
}

// ---------------------------------------------------------------------------
// reduce: sum splits, elu(num/den), merge branches.
// ---------------------------------------------------------------------------
__global__ __launch_bounds__(256) void reduce_kernel(
    const float* __restrict__ num_ws, const float* __restrict__ den_ws,
    float* __restrict__ out)
{
    int gid = blockIdx.x * 256 + threadIdx.x;
    int i = gid >> 6;
    int f4 = (gid & 63) * 4;
    float4 o = {0.f, 0.f, 0.f, 0.f};
    #pragma unroll
    for (int b = 0; b < 2; ++b) {
        float4 num = {0.f, 0.f, 0.f, 0.f};
        float den = 0.f;
        #pragma unroll
        for (int s = 0; s < NSPLIT; ++s) {
            const float4 v = *(const float4*)&num_ws[((size_t)(b * NSPLIT + s) * N_NODES + i) * FOUT + f4];
            num.x += v.x; num.y += v.y; num.z += v.z; num.w += v.w;
            den += den_ws[(size_t)(b * NSPLIT + s) * N_NODES + i];
        }
        float inv = 1.0f / den;
        float e0 = num.x * inv, e1 = num.y * inv, e2 = num.z * inv, e3 = num.w * inv;
        o.x += (e0 > 0.f) ? e0 : expm1f(e0);
        o.y += (e1 > 0.f) ? e1 : expm1f(e1);
        o.z += (e2 > 0.f) ? e2 : expm1f(e2);
        o.w += (e3 > 0.f) ? e3 : expm1f(e3);
    }
    *(float4*)&out[(size_t)i * FOUT + f4] = o;
}

extern "C" void kernel_launch(void* const* d_in, const int* in_sizes, int n_in,
                              void* d_out, int out_size, void* d_ws, size_t ws_size,
                              hipStream_t stream) {
    const float* h    = (const float*)d_in[0];
    const int*   adjn = (const int*)d_in[1];
    const int*   adjd = (const int*)d_in[2];
    const float* Wn   = (const float*)d_in[4];
    const float* a1n  = (const float*)d_in[5];
    const float* a2n  = (const float*)d_in[6];
    const float* Wd   = (const float*)d_in[7];
    const float* a1d  = (const float*)d_in[8];
    const float* a2d  = (const float*)d_in[9];

    char* ws = (char*)d_ws;
    // [0,4M): WhT   [4M,8M): bits   [8M,8M+192K): s1,s2,den
    // [8.25M,12.25M): hb   [12.25M,12.75M): WTb   (dead after wh_gemm)
    // [8.25M,40.25M): num  (overlays hb/WTb; written by attn after wh_gemm)
    u16*  WhT  = (u16*)ws;
    u32*  bits = (u32*)(ws + ((size_t)4 << 20));
    float* s1  = (float*)(ws + ((size_t)8 << 20));
    float* s2  = s1 + 2 * N_NODES;
    float* den = s2 + 2 * N_NODES;
    u16*  hb   = (u16*)(ws + ((size_t)8 << 20) + ((size_t)256 << 10));
    u16*  WTb  = (u16*)(ws + ((size_t)12 << 20) + ((size_t)256 << 10));
    float* num = (float*)(ws + ((size_t)8 << 20) + ((size_t)256 << 10));

    prep_kernel<<<2113, 256, 0, stream>>>(h, Wn, Wd, adjn, adjd, hb, WTb, (u64*)bits, s1);
    wh_gemm_kernel<<<dim3(64, 4, 2), 256, 0, stream>>>(hb, WTb, a1n, a2n, a1d, a2d, WhT, s1, s2);
    attn_kernel<<<dim3(128, NSPLIT, 2), 256, 0, stream>>>(bits, WhT, s1, s2, num, den);
    reduce_kernel<<<1024, 256, 0, stream>>>(num, den, (float*)d_out);
}

// Round 4
// 221.499 us; speedup vs baseline: 1.0306x; 1.0306x over previous
//
#include <hip/hip_runtime.h>

#define N_NODES 4096
#define FIN     512
#define FOUT    256
#define NSPLIT  4
#define NTILES  ((N_NODES / NSPLIT) / 64)   // 16

typedef __attribute__((ext_vector_type(8))) short bf16x8s;
typedef __attribute__((ext_vector_type(4))) float f32x4;
typedef __attribute__((ext_vector_type(8))) unsigned short u16x8;
typedef unsigned short u16;
typedef unsigned int   u32;
typedef unsigned long long u64;

__device__ inline u16 f2b(float f) {
    union { float f; unsigned int u; } v; v.f = f;
    unsigned int r = v.u + 0x7fffu + ((v.u >> 16) & 1u);   // RTNE
    return (u16)(r >> 16);
}

// ---------------------------------------------------------------------------
// prep: [0,1024)    h fp32 -> hb bf16
//       [1024,3072) adj_n|adj_d -> bitmask (int4 loads, per-lane u16 pack)
//       [3072,3136) W_b -> WTb bf16 transposed [n][k]
//       [3136]      zero s1/s2
// ---------------------------------------------------------------------------
__global__ __launch_bounds__(256) void prep_kernel(
    const float* __restrict__ h, const float* __restrict__ Wn,
    const float* __restrict__ Wd,
    const int* __restrict__ adjn, const int* __restrict__ adjd,
    u16* __restrict__ hb, u16* __restrict__ WTb, u16* __restrict__ bits16,
    float* __restrict__ s12)
{
    __shared__ u16 tl[64 * 72];
    const int t = threadIdx.x;
    const int bid = blockIdx.x;

    if (bid < 1024) {                       // h convert
        int idx = (bid * 256 + t) * 8;
        float4 f0 = *(const float4*)&h[idx];
        float4 f1 = *(const float4*)&h[idx + 4];
        u16x8 o;
        o[0]=f2b(f0.x); o[1]=f2b(f0.y); o[2]=f2b(f0.z); o[3]=f2b(f0.w);
        o[4]=f2b(f1.x); o[5]=f2b(f1.y); o[6]=f2b(f1.z); o[7]=f2b(f1.w);
        *(u16x8*)&hb[idx] = o;
    } else if (bid < 3072) {                // adj -> bits, 4096 ints per wave
        const int lane = t & 63, w = t >> 6;
        const long gw = (long)(bid - 1024) * 4 + w;        // 0..8191
        const long base = gw * 4096;
        const int* p = (base < (1L << 24)) ? (adjn + base)
                                           : (adjd + (base - (1L << 24)));
        const int4* src = (const int4*)p + lane * 4;
        u16* dst = bits16 + (base >> 4) + lane;
        #pragma unroll
        for (int s = 0; s < 4; ++s) {
            int4 a = src[s * 256 + 0];
            int4 b = src[s * 256 + 1];
            int4 c = src[s * 256 + 2];
            int4 d = src[s * 256 + 3];
            u32 m = 0;
            m |= (u32)(a.x > 0) << 0;  m |= (u32)(a.y > 0) << 1;
            m |= (u32)(a.z > 0) << 2;  m |= (u32)(a.w > 0) << 3;
            m |= (u32)(b.x > 0) << 4;  m |= (u32)(b.y > 0) << 5;
            m |= (u32)(b.z > 0) << 6;  m |= (u32)(b.w > 0) << 7;
            m |= (u32)(c.x > 0) << 8;  m |= (u32)(c.y > 0) << 9;
            m |= (u32)(c.z > 0) << 10; m |= (u32)(c.w > 0) << 11;
            m |= (u32)(d.x > 0) << 12; m |= (u32)(d.y > 0) << 13;
            m |= (u32)(d.z > 0) << 14; m |= (u32)(d.w > 0) << 15;
            dst[s * 64] = (u16)m;
        }
    } else if (bid < 3136) {                // W transpose+convert, 64x64 tiles
        int id = bid - 3072;
        int kx = id & 7, ny = (id >> 3) & 3, b = id >> 5;
        const float* W = b ? Wd : Wn;
        int k0 = kx * 64, n0 = ny * 64;
        int kr = t >> 2, nc0 = (t & 3) * 16;
        const float* src = W + (size_t)(k0 + kr) * FOUT + n0 + nc0;
        #pragma unroll
        for (int jv = 0; jv < 4; ++jv) {
            float4 f = *(const float4*)(src + jv * 4);
            tl[(nc0 + jv * 4 + 0) * 72 + kr] = f2b(f.x);
            tl[(nc0 + jv * 4 + 1) * 72 + kr] = f2b(f.y);
            tl[(nc0 + jv * 4 + 2) * 72 + kr] = f2b(f.z);
            tl[(nc0 + jv * 4 + 3) * 72 + kr] = f2b(f.w);
        }
        __syncthreads();
        int n = t >> 2, kc0 = (t & 3) * 16;
        u16* dst = WTb + ((size_t)b << 17) + (size_t)(n0 + n) * FIN + k0 + kc0;
        *(uint4*)dst       = *(uint4*)&tl[n * 72 + kc0];
        *(uint4*)(dst + 8) = *(uint4*)&tl[n * 72 + kc0 + 8];
    } else {                                // zero s1,s2 (16384 floats)
        float4 z = {0.f, 0.f, 0.f, 0.f};
        float4* p4 = (float4*)s12;
        #pragma unroll
        for (int k = 0; k < 16; ++k) p4[k * 256 + t] = z;
    }
}

// ---------------------------------------------------------------------------
// wh_gemm: WhT[b][n][i] = (hb @ W_b)[i][n]; epilogue also accumulates
// s1[b][i] += sum_n C[i][n]*a1[n], s2 likewise (atomics across n0-blocks).
// grid (64, 4, 2).
// ---------------------------------------------------------------------------
__global__ __launch_bounds__(256) void wh_gemm_kernel(
    const u16* __restrict__ hb, const u16* __restrict__ WTb,
    const float* __restrict__ a1n, const float* __restrict__ a2n,
    const float* __restrict__ a1d, const float* __restrict__ a2d,
    u16* __restrict__ WhT, float* __restrict__ s1, float* __restrict__ s2)
{
    __shared__ u16 smem[8192];
    u16* a_lds = smem;
    u16* b_lds = smem + 4096;

    const int t = threadIdx.x, lane = t & 63, w = t >> 6;
    const int q = lane >> 4, ln = lane & 15;
    const int i0 = blockIdx.x * 64, n0 = blockIdx.y * 64, b = blockIdx.z;
    const u16* wt = WTb + ((size_t)b << 17);

    f32x4 acc[4];
    #pragma unroll
    for (int i = 0; i < 4; ++i) acc[i] = (f32x4){0.f, 0.f, 0.f, 0.f};

    for (int kt = 0; kt < 8; ++kt) {
        const int k0 = kt * 64;
        __syncthreads();
        #pragma unroll
        for (int it = 0; it < 2; ++it) {
            int chunk = it * 256 + t;
            int r = chunk >> 3, kc = chunk & 7;
            const u16* g = hb + (size_t)(i0 + r) * FIN + k0 + ((kc ^ (r & 7)) * 8);
            u16* l = a_lds + (it * 256 + w * 64) * 8;
            __builtin_amdgcn_global_load_lds(
                (const __attribute__((address_space(1))) void*)g,
                (__attribute__((address_space(3))) void*)l, 16, 0, 0);
        }
        #pragma unroll
        for (int it = 0; it < 2; ++it) {
            int chunk = it * 256 + t;
            int n = chunk >> 3, kc = chunk & 7;
            const u16* g = wt + (size_t)(n0 + n) * FIN + k0 + ((kc ^ (n & 7)) * 8);
            u16* l = b_lds + (it * 256 + w * 64) * 8;
            __builtin_amdgcn_global_load_lds(
                (const __attribute__((address_space(1))) void*)g,
                (__attribute__((address_space(3))) void*)l, 16, 0, 0);
        }
        __syncthreads();
        #pragma unroll
        for (int ks = 0; ks < 2; ++ks) {
            int sw = ((ks * 4 + q) ^ (ln & 7)) * 8;
            bf16x8s af = *(const bf16x8s*)&a_lds[(w * 16 + ln) * 64 + sw];
            #pragma unroll
            for (int nt = 0; nt < 4; ++nt) {
                bf16x8s bfv = *(const bf16x8s*)&b_lds[(nt * 16 + ln) * 64 + sw];
                acc[nt] = __builtin_amdgcn_mfma_f32_16x16x32_bf16(af, bfv, acc[nt], 0, 0, 0);
            }
        }
    }

    {
        const float* a1 = b ? a1d : a1n;
        const float* a2 = b ? a2d : a2n;
        float s1p[4] = {0.f, 0.f, 0.f, 0.f};
        float s2p[4] = {0.f, 0.f, 0.f, 0.f};
        #pragma unroll
        for (int nt = 0; nt < 4; ++nt) {
            float va1 = a1[n0 + nt * 16 + ln];
            float va2 = a2[n0 + nt * 16 + ln];
            #pragma unroll
            for (int r = 0; r < 4; ++r) {
                s1p[r] += acc[nt][r] * va1;
                s2p[r] += acc[nt][r] * va2;
            }
        }
        #pragma unroll
        for (int r = 0; r < 4; ++r) {
            #pragma unroll
            for (int off = 8; off >= 1; off >>= 1) {
                s1p[r] += __shfl_xor(s1p[r], off);
                s2p[r] += __shfl_xor(s2p[r], off);
            }
            if (ln == 0) {
                int row = i0 + w * 16 + q * 4 + r;
                atomicAdd(&s1[b * N_NODES + row], s1p[r]);
                atomicAdd(&s2[b * N_NODES + row], s2p[r]);
            }
        }
    }

    __syncthreads();
    #pragma unroll
    for (int nt = 0; nt < 4; ++nt)
        #pragma unroll
        for (int r = 0; r < 4; ++r)
            smem[(nt * 16 + ln) * 72 + (w * 16 + q * 4 + r)] = f2b(acc[nt][r]);
    __syncthreads();
    {
        const int nl = t >> 2, is = (t & 3) * 16;
        u16* dst = WhT + ((size_t)b << 20) + (size_t)(n0 + nl) * N_NODES + i0 + is;
        *(uint4*)dst       = *(uint4*)&smem[nl * 72 + is];
        *(uint4*)(dst + 8) = *(uint4*)&smem[nl * 72 + is + 8];
    }
}

// ---------------------------------------------------------------------------
// attn: 64 rows x 1024-j per block (m=64 halves WhT re-read); bits from L2;
// bits/s2 prefetched a tile ahead. grid (64, NSPLIT, 2).
// ---------------------------------------------------------------------------
__global__ __launch_bounds__(256) void attn_kernel(
    const u32* __restrict__ bits,
    const u16* __restrict__ WhT,
    const float* __restrict__ s1, const float* __restrict__ s2,
    float* __restrict__ num_ws, float* __restrict__ den_ws)
{
    __shared__ u16 wht_lds[256 * 64];   // swizzled [n][kchunk^(n&7)], 32 KB
    __shared__ u16 p_lds[64 * 64];      // swizzled, 8 KB
    __shared__ float den_lds[64];

    const int t = threadIdx.x, lane = t & 63, w = t >> 6;
    const int q = lane >> 4, ln = lane & 15;
    const int b = blockIdx.z, split = blockIdx.y;
    const int i0 = blockIdx.x * 64;

    const u16* whtB = WhT + ((size_t)b << 20);
    const float* s1b = s1 + b * N_NODES;
    const float* s2b = s2 + b * N_NODES;

    const int pr = t >> 3;              // P row 0..31 (also handles pr+32)
    const int cw = t & 7;               // P k-chunk 0..7
    const int pc = cw * 8;
    const int bsh = (cw & 3) * 8;
    const float s1v0 = s1b[i0 + pr];
    const float s1v1 = s1b[i0 + pr + 32];
    const u32* bitrow0 = bits + (size_t)b * (N_NODES * (N_NODES / 32))
                              + (size_t)(i0 + pr) * (N_NODES / 32) + (cw >> 2);
    const u32* bitrow1 = bitrow0 + 32 * (N_NODES / 32);

    if (t < 64) den_lds[t] = 0.f;

    f32x4 acc[4][4];
    #pragma unroll
    for (int mt = 0; mt < 4; ++mt)
        #pragma unroll
        for (int nt = 0; nt < 4; ++nt) acc[mt][nt] = (f32x4){0.f, 0.f, 0.f, 0.f};

    const int jbase = split * (N_NODES / NSPLIT);
    u32 bw0_pf = bitrow0[jbase >> 5];
    u32 bw1_pf = bitrow1[jbase >> 5];
    float4 sv0_pf = *(const float4*)&s2b[jbase + pc];
    float4 sv1_pf = *(const float4*)&s2b[jbase + pc + 4];

    for (int jt = 0; jt < NTILES; ++jt) {
        const int j0 = jbase + jt * 64;
        __syncthreads();
        #pragma unroll
        for (int it = 0; it < 8; ++it) {   // stage 256n x 64j WhT tile
            int chunk = it * 256 + t;
            int n = chunk >> 3, kc = chunk & 7;
            const u16* g = whtB + (size_t)n * N_NODES + j0 + ((kc ^ (n & 7)) * 8);
            u16* l = wht_lds + (it * 256 + w * 64) * 8;
            __builtin_amdgcn_global_load_lds(
                (const __attribute__((address_space(1))) void*)g,
                (__attribute__((address_space(3))) void*)l, 16, 0, 0);
        }
        u32 bw0 = bw0_pf, bw1 = bw1_pf;
        float4 sv0 = sv0_pf, sv1 = sv1_pf;
        if (jt < NTILES - 1) {             // prefetch next tile
            bw0_pf = bitrow0[(j0 + 64) >> 5];
            bw1_pf = bitrow1[(j0 + 64) >> 5];
            sv0_pf = *(const float4*)&s2b[j0 + 64 + pc];
            sv1_pf = *(const float4*)&s2b[j0 + 64 + pc + 4];
        }
        u32 m0 = (bw0 >> bsh) & 0xffu;
        u32 m1 = (bw1 >> bsh) & 0xffu;
        float svf[8] = {sv0.x, sv0.y, sv0.z, sv0.w, sv1.x, sv1.y, sv1.z, sv1.w};
        float d0 = 0.f, d1 = 0.f;
        u16x8 pk0, pk1;
        #pragma unroll
        for (int jj = 0; jj < 8; ++jj) {
            float sv = svf[jj];
            float x0 = s1v0 + sv, x1 = s1v1 + sv;
            float p0 = ((m0 >> jj) & 1u) ? __expf(fmaxf(x0, 0.2f * x0)) : 0.f;
            float p1 = ((m1 >> jj) & 1u) ? __expf(fmaxf(x1, 0.2f * x1)) : 0.f;
            d0 += p0; d1 += p1;
            pk0[jj] = f2b(p0); pk1[jj] = f2b(p1);
        }
        d0 += __shfl_down(d0, 4, 8); d1 += __shfl_down(d1, 4, 8);
        d0 += __shfl_down(d0, 2, 8); d1 += __shfl_down(d1, 2, 8);
        d0 += __shfl_down(d0, 1, 8); d1 += __shfl_down(d1, 1, 8);
        if ((t & 7) == 0) { den_lds[pr] += d0; den_lds[pr + 32] += d1; }
        int swp = ((cw ^ (pr & 7)) * 8);
        *(u16x8*)&p_lds[pr * 64 + swp] = pk0;
        *(u16x8*)&p_lds[(pr + 32) * 64 + swp] = pk1;
        __syncthreads();
        #pragma unroll
        for (int ks = 0; ks < 2; ++ks) {
            int sw = ((ks * 4 + q) ^ (ln & 7)) * 8;
            bf16x8s af[4];
            #pragma unroll
            for (int mt = 0; mt < 4; ++mt)
                af[mt] = *(const bf16x8s*)&p_lds[(mt * 16 + ln) * 64 + sw];
            #pragma unroll
            for (int nt = 0; nt < 4; ++nt) {
                bf16x8s bfv = *(const bf16x8s*)&wht_lds[(w * 64 + nt * 16 + ln) * 64 + sw];
                #pragma unroll
                for (int mt = 0; mt < 4; ++mt)
                    acc[mt][nt] = __builtin_amdgcn_mfma_f32_16x16x32_bf16(af[mt], bfv, acc[mt][nt], 0, 0, 0);
            }
        }
    }
    const size_t pbase = (size_t)(b * NSPLIT + split) * N_NODES;
    #pragma unroll
    for (int mt = 0; mt < 4; ++mt)
        #pragma unroll
        for (int r = 0; r < 4; ++r) {
            int row = mt * 16 + q * 4 + r;
            #pragma unroll
            for (int nt = 0; nt < 4; ++nt)
                num_ws[(pbase + i0 + row) * FOUT + w * 64 + nt * 16 + ln] = acc[mt][nt][r];
        }
    if (t < 64) den_ws[pbase + i0 + t] = den_lds[t];
}

// ---------------------------------------------------------------------------
// reduce: sum splits, elu(num/den), merge branches.
// ---------------------------------------------------------------------------
__global__ __launch_bounds__(256) void reduce_kernel(
    const float* __restrict__ num_ws, const float* __restrict__ den_ws,
    float* __restrict__ out)
{
    int gid = blockIdx.x * 256 + threadIdx.x;
    int i = gid >> 6;
    int f4 = (gid & 63) * 4;
    float4 o = {0.f, 0.f, 0.f, 0.f};
    #pragma unroll
    for (int b = 0; b < 2; ++b) {
        float4 num = {0.f, 0.f, 0.f, 0.f};
        float den = 0.f;
        #pragma unroll
        for (int s = 0; s < NSPLIT; ++s) {
            const float4 v = *(const float4*)&num_ws[((size_t)(b * NSPLIT + s) * N_NODES + i) * FOUT + f4];
            num.x += v.x; num.y += v.y; num.z += v.z; num.w += v.w;
            den += den_ws[(size_t)(b * NSPLIT + s) * N_NODES + i];
        }
        float inv = 1.0f / den;
        float e0 = num.x * inv, e1 = num.y * inv, e2 = num.z * inv, e3 = num.w * inv;
        o.x += (e0 > 0.f) ? e0 : expm1f(e0);
        o.y += (e1 > 0.f) ? e1 : expm1f(e1);
        o.z += (e2 > 0.f) ? e2 : expm1f(e2);
        o.w += (e3 > 0.f) ? e3 : expm1f(e3);
    }
    *(float4*)&out[(size_t)i * FOUT + f4] = o;
}

extern "C" void kernel_launch(void* const* d_in, const int* in_sizes, int n_in,
                              void* d_out, int out_size, void* d_ws, size_t ws_size,
                              hipStream_t stream) {
    const float* h    = (const float*)d_in[0];
    const int*   adjn = (const int*)d_in[1];
    const int*   adjd = (const int*)d_in[2];
    const float* Wn   = (const float*)d_in[4];
    const float* a1n  = (const float*)d_in[5];
    const float* a2n  = (const float*)d_in[6];
    const float* Wd   = (const float*)d_in[7];
    const float* a1d  = (const float*)d_in[8];
    const float* a2d  = (const float*)d_in[9];

    char* ws = (char*)d_ws;
    // [0,4M): WhT   [4M,8M): bits   [8M,8M+192K): s1,s2,den
    // [8.25M,12.25M): hb   [12.25M,12.75M): WTb   (dead after wh_gemm)
    // [8.25M,40.25M): num  (overlays hb/WTb; written by attn after wh_gemm)
    u16*  WhT  = (u16*)ws;
    u16*  bits = (u16*)(ws + ((size_t)4 << 20));
    float* s1  = (float*)(ws + ((size_t)8 << 20));
    float* s2  = s1 + 2 * N_NODES;
    float* den = s2 + 2 * N_NODES;
    u16*  hb   = (u16*)(ws + ((size_t)8 << 20) + ((size_t)256 << 10));
    u16*  WTb  = (u16*)(ws + ((size_t)12 << 20) + ((size_t)256 << 10));
    float* num = (float*)(ws + ((size_t)8 << 20) + ((size_t)256 << 10));

    prep_kernel<<<3137, 256, 0, stream>>>(h, Wn, Wd, adjn, adjd, hb, WTb, bits, s1);
    wh_gemm_kernel<<<dim3(64, 4, 2), 256, 0, stream>>>(hb, WTb, a1n, a2n, a1d, a2d, WhT, s1, s2);
    attn_kernel<<<dim3(64, NSPLIT, 2), 256, 0, stream>>>((const u32*)bits, WhT, s1, s2, num, den);
    reduce_kernel<<<1024, 256, 0, stream>>>(num, den, (float*)d_out);
}